// Round 2
// baseline (125.200 us; speedup 1.0000x reference)
//
#include <hip/hip_runtime.h>

// Problem constants (from reference setup_inputs): B=8, L=4096, D=256, f32.
#define BATCH 8
#define SEQ   4096
#define DIM   256

// Each thread owns 4 consecutive d-columns (float4 loads, 16B/lane).
// A wave (64 lanes) covers one tile's full DIM=256. Block = 4 waves = 4 tiles.

// ---------------------------------------------------------------------------
// Kernel 1: per-(b, tile) affine aggregate, 4 columns/thread via float4.
// ---------------------------------------------------------------------------
__global__ __launch_bounds__(256) void k_tile_agg(
    const float* __restrict__ Ar, const float* __restrict__ Ai,
    const float* __restrict__ Xr, const float* __restrict__ Xi,
    float4* __restrict__ agg, int NT, int T)
{
    int wave = threadIdx.x >> 6;
    int lane = threadIdx.x & 63;
    int tile = blockIdx.x * 4 + wave;        // in [0, BATCH*NT)
    int b = tile / NT;
    int j = tile - b * NT;
    int d = lane * 4;

    size_t base = ((size_t)b * SEQ + (size_t)j * T) * DIM + d;

    float ar[4], ai[4], xr[4], xi[4];
#pragma unroll
    for (int k = 0; k < 4; ++k) { ar[k] = 1.f; ai[k] = 0.f; xr[k] = 0.f; xi[k] = 0.f; }

#pragma unroll 4
    for (int t = 0; t < T; ++t) {
        size_t idx = base + (size_t)t * DIM;
        float4 car = *(const float4*)(Ar + idx);
        float4 cai = *(const float4*)(Ai + idx);
        float4 cxr = *(const float4*)(Xr + idx);
        float4 cxi = *(const float4*)(Xi + idx);
        const float* pab = (const float*)&car;
        const float* pai = (const float*)&cai;
        const float* pxr = (const float*)&cxr;
        const float* pxi = (const float*)&cxi;
#pragma unroll
        for (int k = 0; k < 4; ++k) {
            float a_r = pab[k], a_i = pai[k], x_r = pxr[k], x_i = pxi[k];
            float nar = a_r * ar[k] - a_i * ai[k];
            float nai = a_r * ai[k] + a_i * ar[k];
            float nxr = a_r * xr[k] - a_i * xi[k] + x_r;
            float nxi = a_r * xi[k] + a_i * xr[k] + x_i;
            ar[k] = nar; ai[k] = nai; xr[k] = nxr; xi[k] = nxi;
        }
    }
    size_t o = ((size_t)b * NT + j) * DIM + d;
#pragma unroll
    for (int k = 0; k < 4; ++k)
        agg[o + k] = make_float4(ar[k], ai[k], xr[k], xi[k]);
}

// ---------------------------------------------------------------------------
// Kernel 2: exclusive scan of tile aggregates along j for each (b,d).
// One block per b, thread = d, serial over j (loads coalesced across d,
// independent addresses so prefetchable).
// ---------------------------------------------------------------------------
__global__ __launch_bounds__(DIM) void k_scan_agg(float4* __restrict__ agg, int NT)
{
    int b = blockIdx.x;
    int d = threadIdx.x;

    float ar = 1.f, ai = 0.f, xr = 0.f, xi = 0.f;   // composite of tiles < j
    for (int j = 0; j < NT; ++j) {
        size_t o = ((size_t)b * NT + j) * DIM + d;
        float4 v = agg[o];                          // tile j aggregate (a, x)
        agg[o] = make_float4(xr, xi, 0.f, 0.f);     // incoming y for tile j
        float nar = v.x * ar - v.y * ai;
        float nai = v.x * ai + v.y * ar;
        float nxr = v.x * xr - v.y * xi + v.z;
        float nxi = v.x * xi + v.y * xr + v.w;
        ar = nar; ai = nai; xr = nxr; xi = nxi;
    }
}

// ---------------------------------------------------------------------------
// Kernel 3: seed y from tile prefix, recompute recurrence, write out.
// Output [B,L,D,2]: each lane writes two contiguous float4 (32B/lane).
// ---------------------------------------------------------------------------
__global__ __launch_bounds__(256) void k_apply(
    const float* __restrict__ Ar, const float* __restrict__ Ai,
    const float* __restrict__ Xr, const float* __restrict__ Xi,
    const float4* __restrict__ agg, float* __restrict__ outf, int NT, int T)
{
    int wave = threadIdx.x >> 6;
    int lane = threadIdx.x & 63;
    int tile = blockIdx.x * 4 + wave;
    int b = tile / NT;
    int j = tile - b * NT;
    int d = lane * 4;

    float yr[4], yi[4];
    size_t o = ((size_t)b * NT + j) * DIM + d;
#pragma unroll
    for (int k = 0; k < 4; ++k) {
        float4 p = agg[o + k];
        yr[k] = p.x; yi[k] = p.y;
    }

    size_t base = ((size_t)b * SEQ + (size_t)j * T) * DIM + d;
#pragma unroll 4
    for (int t = 0; t < T; ++t) {
        size_t idx = base + (size_t)t * DIM;
        float4 car = *(const float4*)(Ar + idx);
        float4 cai = *(const float4*)(Ai + idx);
        float4 cxr = *(const float4*)(Xr + idx);
        float4 cxi = *(const float4*)(Xi + idx);
        const float* pab = (const float*)&car;
        const float* pai = (const float*)&cai;
        const float* pxr = (const float*)&cxr;
        const float* pxi = (const float*)&cxi;
#pragma unroll
        for (int k = 0; k < 4; ++k) {
            float nyr = pab[k] * yr[k] - pai[k] * yi[k] + pxr[k];
            float nyi = pab[k] * yi[k] + pai[k] * yr[k] + pxi[k];
            yr[k] = nyr; yi[k] = nyi;
        }
        float4 o1 = make_float4(yr[0], yi[0], yr[1], yi[1]);
        float4 o2 = make_float4(yr[2], yi[2], yr[3], yi[3]);
        float* po = outf + 2 * idx;
        *(float4*)(po)     = o1;
        *(float4*)(po + 4) = o2;
    }
}

extern "C" void kernel_launch(void* const* d_in, const int* in_sizes, int n_in,
                              void* d_out, int out_size, void* d_ws, size_t ws_size,
                              hipStream_t stream)
{
    const float* Ar = (const float*)d_in[0];
    const float* Ai = (const float*)d_in[1];
    const float* Xr = (const float*)d_in[2];
    const float* Xi = (const float*)d_in[3];
    float* outf = (float*)d_out;
    float4* agg = (float4*)d_ws;

    // Largest NT whose aggregate buffer fits in d_ws (bytes = B*NT*DIM*16).
    int NT = 256;
    while (NT > 4 && (size_t)BATCH * NT * DIM * sizeof(float4) > ws_size) NT >>= 1;
    int T = SEQ / NT;

    dim3 block(256);
    dim3 grid1((BATCH * NT) / 4);   // 4 tiles (waves) per block

    k_tile_agg<<<grid1, block, 0, stream>>>(Ar, Ai, Xr, Xi, agg, NT, T);
    k_scan_agg<<<BATCH, dim3(DIM), 0, stream>>>(agg, NT);
    k_apply<<<grid1, block, 0, stream>>>(Ar, Ai, Xr, Xi, agg, outf, NT, T);
}

// Round 4
// 79.947 us; speedup vs baseline: 1.5660x; 1.5660x over previous
//
#include <hip/hip_runtime.h>

// Problem constants (from reference setup_inputs): B=8, L=4096, D=256, f32.
#define BATCH 8
#define SEQ   4096
#define DIM   256

// Native clang vector type — required by __builtin_nontemporal_store
// (HIP's float4 class type is rejected).
typedef float floatx4 __attribute__((ext_vector_type(4)));

// Tile decomposition: NT tiles of T timesteps per batch. A tile is owned by
// one wave: 64 lanes x 4 consecutive d-columns (float4 loads, 16B/lane).

// ---------------------------------------------------------------------------
// Kernel 1: per-(b, tile) affine aggregate, 4 columns/thread via float4.
// ---------------------------------------------------------------------------
template <int NT, int T>
__global__ __launch_bounds__(256) void k_tile_agg(
    const float* __restrict__ Ar, const float* __restrict__ Ai,
    const float* __restrict__ Xr, const float* __restrict__ Xi,
    float4* __restrict__ agg)
{
    int wave = threadIdx.x >> 6;
    int lane = threadIdx.x & 63;
    int tile = blockIdx.x * 4 + wave;        // in [0, BATCH*NT)
    int b = tile / NT;
    int j = tile - b * NT;
    int d = lane * 4;

    size_t base = ((size_t)b * SEQ + (size_t)j * T) * DIM + d;

    float ar[4], ai[4], xr[4], xi[4];
#pragma unroll
    for (int k = 0; k < 4; ++k) { ar[k] = 1.f; ai[k] = 0.f; xr[k] = 0.f; xi[k] = 0.f; }

#pragma unroll 8
    for (int t = 0; t < T; ++t) {
        size_t idx = base + (size_t)t * DIM;
        float4 car = *(const float4*)(Ar + idx);
        float4 cai = *(const float4*)(Ai + idx);
        float4 cxr = *(const float4*)(Xr + idx);
        float4 cxi = *(const float4*)(Xi + idx);
        const float* pab = (const float*)&car;
        const float* pai = (const float*)&cai;
        const float* pxr = (const float*)&cxr;
        const float* pxi = (const float*)&cxi;
#pragma unroll
        for (int k = 0; k < 4; ++k) {
            float a_r = pab[k], a_i = pai[k], x_r = pxr[k], x_i = pxi[k];
            float nar = a_r * ar[k] - a_i * ai[k];
            float nai = a_r * ai[k] + a_i * ar[k];
            float nxr = a_r * xr[k] - a_i * xi[k] + x_r;
            float nxi = a_r * xi[k] + a_i * xr[k] + x_i;
            ar[k] = nar; ai[k] = nai; xr[k] = nxr; xi[k] = nxi;
        }
    }
    size_t o = ((size_t)b * NT + j) * DIM + d;
#pragma unroll
    for (int k = 0; k < 4; ++k)
        agg[o + k] = make_float4(ar[k], ai[k], xr[k], xi[k]);
}

// ---------------------------------------------------------------------------
// Kernel 2: wave-parallel exclusive scan of tile aggregates along j.
// One wave per (b,d) column. Lane owns NTPL = NT/64 consecutive tiles:
// serial-combine them, wave-level Hillis-Steele inclusive scan (6 shfl
// steps), shift to exclusive, then walk the local tiles writing each
// tile's incoming prefix (y-seed) back into agg.
// ---------------------------------------------------------------------------
template <int NT>
__global__ __launch_bounds__(256) void k_scan_agg(float4* __restrict__ agg)
{
    constexpr int NTPL = NT / 64;
    int lane = threadIdx.x & 63;
    int col  = blockIdx.x * 4 + (threadIdx.x >> 6);   // in [0, BATCH*DIM)
    int b = col >> 8;          // / DIM
    int d = col & 255;         // % DIM

    // Load this lane's tiles and compose them (earlier tile = left operand).
    float4 v[NTPL];
    float lar = 1.f, lai = 0.f, lxr = 0.f, lxi = 0.f;
#pragma unroll
    for (int m = 0; m < NTPL; ++m) {
        v[m] = agg[((size_t)b * NT + lane * NTPL + m) * DIM + d];
        // cur = combine(left=cur_prev, right=v[m]) : a' = va*a, x' = va*x + vx
        float nar = v[m].x * lar - v[m].y * lai;
        float nai = v[m].x * lai + v[m].y * lar;
        float nxr = v[m].x * lxr - v[m].y * lxi + v[m].z;
        float nxi = v[m].x * lxi + v[m].y * lxr + v[m].w;
        lar = nar; lai = nai; lxr = nxr; lxi = nxi;
    }

    // Wave inclusive scan.
    float ar = lar, ai = lai, xr = lxr, xi = lxi;
#pragma unroll
    for (int off = 1; off < 64; off <<= 1) {
        float par = __shfl_up(ar, (unsigned)off, 64);
        float pai = __shfl_up(ai, (unsigned)off, 64);
        float pxr = __shfl_up(xr, (unsigned)off, 64);
        float pxi = __shfl_up(xi, (unsigned)off, 64);
        if (lane >= off) {
            // cur = combine(left=p, right=cur): a' = a*pa, x' = a*px + x
            float nar = ar * par - ai * pai;
            float nai = ar * pai + ai * par;
            float nxr = ar * pxr - ai * pxi + xr;
            float nxi = ar * pxi + ai * pxr + xi;
            ar = nar; ai = nai; xr = nxr; xi = nxi;
        }
    }

    // Shift to exclusive (lane 0 = identity).
    float ear = __shfl_up(ar, 1u, 64);
    float eai = __shfl_up(ai, 1u, 64);
    float exr = __shfl_up(xr, 1u, 64);
    float exi = __shfl_up(xi, 1u, 64);
    if (lane == 0) { ear = 1.f; eai = 0.f; exr = 0.f; exi = 0.f; }

    // Walk local tiles: write incoming y, then fold tile in.
#pragma unroll
    for (int m = 0; m < NTPL; ++m) {
        agg[((size_t)b * NT + lane * NTPL + m) * DIM + d] =
            make_float4(exr, exi, 0.f, 0.f);
        float nar = v[m].x * ear - v[m].y * eai;
        float nai = v[m].x * eai + v[m].y * ear;
        float nxr = v[m].x * exr - v[m].y * exi + v[m].z;
        float nxi = v[m].x * exi + v[m].y * exr + v[m].w;
        ear = nar; eai = nai; exr = nxr; exi = nxi;
    }
}

// ---------------------------------------------------------------------------
// Kernel 3: seed y from tile prefix, recompute recurrence, write out.
// Output [B,L,D,2]: each lane writes two contiguous float4 (32B/lane),
// nontemporal (write-once, never re-read).
// ---------------------------------------------------------------------------
template <int NT, int T>
__global__ __launch_bounds__(256) void k_apply(
    const float* __restrict__ Ar, const float* __restrict__ Ai,
    const float* __restrict__ Xr, const float* __restrict__ Xi,
    const float4* __restrict__ agg, float* __restrict__ outf)
{
    int wave = threadIdx.x >> 6;
    int lane = threadIdx.x & 63;
    int tile = blockIdx.x * 4 + wave;
    int b = tile / NT;
    int j = tile - b * NT;
    int d = lane * 4;

    float yr[4], yi[4];
    size_t o = ((size_t)b * NT + j) * DIM + d;
#pragma unroll
    for (int k = 0; k < 4; ++k) {
        float4 p = agg[o + k];
        yr[k] = p.x; yi[k] = p.y;
    }

    size_t base = ((size_t)b * SEQ + (size_t)j * T) * DIM + d;
#pragma unroll 8
    for (int t = 0; t < T; ++t) {
        size_t idx = base + (size_t)t * DIM;
        float4 car = *(const float4*)(Ar + idx);
        float4 cai = *(const float4*)(Ai + idx);
        float4 cxr = *(const float4*)(Xr + idx);
        float4 cxi = *(const float4*)(Xi + idx);
        const float* pab = (const float*)&car;
        const float* pai = (const float*)&cai;
        const float* pxr = (const float*)&cxr;
        const float* pxi = (const float*)&cxi;
#pragma unroll
        for (int k = 0; k < 4; ++k) {
            float nyr = pab[k] * yr[k] - pai[k] * yi[k] + pxr[k];
            float nyi = pab[k] * yi[k] + pai[k] * yr[k] + pxi[k];
            yr[k] = nyr; yi[k] = nyi;
        }
        floatx4 o1 = (floatx4){yr[0], yi[0], yr[1], yi[1]};
        floatx4 o2 = (floatx4){yr[2], yi[2], yr[3], yi[3]};
        float* po = outf + 2 * idx;
        __builtin_nontemporal_store(o1, (floatx4*)(po));
        __builtin_nontemporal_store(o2, (floatx4*)(po + 4));
    }
}

extern "C" void kernel_launch(void* const* d_in, const int* in_sizes, int n_in,
                              void* d_out, int out_size, void* d_ws, size_t ws_size,
                              hipStream_t stream)
{
    const float* Ar = (const float*)d_in[0];
    const float* Ai = (const float*)d_in[1];
    const float* Xr = (const float*)d_in[2];
    const float* Xi = (const float*)d_in[3];
    float* outf = (float*)d_out;
    float4* agg = (float4*)d_ws;

    dim3 block(256);

    if (ws_size >= (size_t)BATCH * 256 * DIM * sizeof(float4)) {
        constexpr int NT = 256, T = SEQ / 256;
        dim3 grid1((BATCH * NT) / 4);
        k_tile_agg<NT, T><<<grid1, block, 0, stream>>>(Ar, Ai, Xr, Xi, agg);
        k_scan_agg<NT><<<(BATCH * DIM) / 4, block, 0, stream>>>(agg);
        k_apply<NT, T><<<grid1, block, 0, stream>>>(Ar, Ai, Xr, Xi, agg, outf);
    } else {
        constexpr int NT = 64, T = SEQ / 64;
        dim3 grid1((BATCH * NT) / 4);
        k_tile_agg<NT, T><<<grid1, block, 0, stream>>>(Ar, Ai, Xr, Xi, agg);
        k_scan_agg<NT><<<(BATCH * DIM) / 4, block, 0, stream>>>(agg);
        k_apply<NT, T><<<grid1, block, 0, stream>>>(Ar, Ai, Xr, Xi, agg, outf);
    }
}

// Round 5
// 71.740 us; speedup vs baseline: 1.7452x; 1.1144x over previous
//
#include <hip/hip_runtime.h>

// Problem constants (from reference setup_inputs): B=8, L=4096, D=256, f32.
#define BATCH 8
#define SEQ   4096
#define DIM   256

// Native clang vector type — required by __builtin_nontemporal_store.
typedef float floatx4 __attribute__((ext_vector_type(4)));

// Tile decomposition: NT tiles of T timesteps per batch. A tile is owned by
// one wave: 64 lanes x 4 consecutive d-columns (float4 loads, 16B/lane).
// G: load-batch depth — G iterations' loads issued before any compute, to
// keep G*4 float4 loads in flight per lane (fights latency-boundedness;
// R4 showed VGPR=44 -> only 1 iteration in flight -> 1.5 TB/s).

// ---------------------------------------------------------------------------
// Kernel 1: per-(b, tile) affine aggregate, 4 columns/thread via float4.
// ---------------------------------------------------------------------------
template <int NT, int T, int G>
__global__ __launch_bounds__(256) void k_tile_agg(
    const float* __restrict__ Ar, const float* __restrict__ Ai,
    const float* __restrict__ Xr, const float* __restrict__ Xi,
    float4* __restrict__ agg)
{
    int wave = threadIdx.x >> 6;
    int lane = threadIdx.x & 63;
    int tile = blockIdx.x * 4 + wave;        // in [0, BATCH*NT)
    int b = tile / NT;
    int j = tile - b * NT;
    int d = lane * 4;

    size_t base = ((size_t)b * SEQ + (size_t)j * T) * DIM + d;

    float ar[4], ai[4], xr[4], xi[4];
#pragma unroll
    for (int k = 0; k < 4; ++k) { ar[k] = 1.f; ai[k] = 0.f; xr[k] = 0.f; xi[k] = 0.f; }

    for (int t0 = 0; t0 < T; t0 += G) {
        float4 Lar[G], Lai[G], Lxr[G], Lxi[G];
#pragma unroll
        for (int g = 0; g < G; ++g) {
            size_t idx = base + (size_t)(t0 + g) * DIM;
            Lar[g] = *(const float4*)(Ar + idx);
            Lai[g] = *(const float4*)(Ai + idx);
            Lxr[g] = *(const float4*)(Xr + idx);
            Lxi[g] = *(const float4*)(Xi + idx);
        }
#pragma unroll
        for (int g = 0; g < G; ++g) {
            const float* pab = (const float*)&Lar[g];
            const float* pai = (const float*)&Lai[g];
            const float* pxr = (const float*)&Lxr[g];
            const float* pxi = (const float*)&Lxi[g];
#pragma unroll
            for (int k = 0; k < 4; ++k) {
                float a_r = pab[k], a_i = pai[k], x_r = pxr[k], x_i = pxi[k];
                float nar = a_r * ar[k] - a_i * ai[k];
                float nai = a_r * ai[k] + a_i * ar[k];
                float nxr = a_r * xr[k] - a_i * xi[k] + x_r;
                float nxi = a_r * xi[k] + a_i * xr[k] + x_i;
                ar[k] = nar; ai[k] = nai; xr[k] = nxr; xi[k] = nxi;
            }
        }
    }
    size_t o = ((size_t)b * NT + j) * DIM + d;
#pragma unroll
    for (int k = 0; k < 4; ++k)
        agg[o + k] = make_float4(ar[k], ai[k], xr[k], xi[k]);
}

// ---------------------------------------------------------------------------
// Kernel 2: wave-parallel exclusive scan of tile aggregates along j.
// One wave per (b,d) column. Lane owns NTPL = NT/64 consecutive tiles.
// ---------------------------------------------------------------------------
template <int NT>
__global__ __launch_bounds__(256) void k_scan_agg(float4* __restrict__ agg)
{
    constexpr int NTPL = NT / 64;
    int lane = threadIdx.x & 63;
    int col  = blockIdx.x * 4 + (threadIdx.x >> 6);   // in [0, BATCH*DIM)
    int b = col >> 8;          // / DIM
    int d = col & 255;         // % DIM

    float4 v[NTPL];
    float lar = 1.f, lai = 0.f, lxr = 0.f, lxi = 0.f;
#pragma unroll
    for (int m = 0; m < NTPL; ++m) {
        v[m] = agg[((size_t)b * NT + lane * NTPL + m) * DIM + d];
        float nar = v[m].x * lar - v[m].y * lai;
        float nai = v[m].x * lai + v[m].y * lar;
        float nxr = v[m].x * lxr - v[m].y * lxi + v[m].z;
        float nxi = v[m].x * lxi + v[m].y * lxr + v[m].w;
        lar = nar; lai = nai; lxr = nxr; lxi = nxi;
    }

    float ar = lar, ai = lai, xr = lxr, xi = lxi;
#pragma unroll
    for (int off = 1; off < 64; off <<= 1) {
        float par = __shfl_up(ar, (unsigned)off, 64);
        float pai = __shfl_up(ai, (unsigned)off, 64);
        float pxr = __shfl_up(xr, (unsigned)off, 64);
        float pxi = __shfl_up(xi, (unsigned)off, 64);
        if (lane >= off) {
            float nar = ar * par - ai * pai;
            float nai = ar * pai + ai * par;
            float nxr = ar * pxr - ai * pxi + xr;
            float nxi = ar * pxi + ai * pxr + xi;
            ar = nar; ai = nai; xr = nxr; xi = nxi;
        }
    }

    float ear = __shfl_up(ar, 1u, 64);
    float eai = __shfl_up(ai, 1u, 64);
    float exr = __shfl_up(xr, 1u, 64);
    float exi = __shfl_up(xi, 1u, 64);
    if (lane == 0) { ear = 1.f; eai = 0.f; exr = 0.f; exi = 0.f; }

#pragma unroll
    for (int m = 0; m < NTPL; ++m) {
        agg[((size_t)b * NT + lane * NTPL + m) * DIM + d] =
            make_float4(exr, exi, 0.f, 0.f);
        float nar = v[m].x * ear - v[m].y * eai;
        float nai = v[m].x * eai + v[m].y * ear;
        float nxr = v[m].x * exr - v[m].y * exi + v[m].z;
        float nxi = v[m].x * exi + v[m].y * exr + v[m].w;
        ear = nar; eai = nai; exr = nxr; exi = nxi;
    }
}

// ---------------------------------------------------------------------------
// Kernel 3: seed y from tile prefix, recompute recurrence, write out.
// Output [B,L,D,2]: two contiguous float4 per lane per t, nontemporal.
// Same G-batched loading as kernel 1.
// ---------------------------------------------------------------------------
template <int NT, int T, int G>
__global__ __launch_bounds__(256) void k_apply(
    const float* __restrict__ Ar, const float* __restrict__ Ai,
    const float* __restrict__ Xr, const float* __restrict__ Xi,
    const float4* __restrict__ agg, float* __restrict__ outf)
{
    int wave = threadIdx.x >> 6;
    int lane = threadIdx.x & 63;
    int tile = blockIdx.x * 4 + wave;
    int b = tile / NT;
    int j = tile - b * NT;
    int d = lane * 4;

    float yr[4], yi[4];
    size_t o = ((size_t)b * NT + j) * DIM + d;
#pragma unroll
    for (int k = 0; k < 4; ++k) {
        float4 p = agg[o + k];
        yr[k] = p.x; yi[k] = p.y;
    }

    size_t base = ((size_t)b * SEQ + (size_t)j * T) * DIM + d;
    for (int t0 = 0; t0 < T; t0 += G) {
        float4 Lar[G], Lai[G], Lxr[G], Lxi[G];
#pragma unroll
        for (int g = 0; g < G; ++g) {
            size_t idx = base + (size_t)(t0 + g) * DIM;
            Lar[g] = *(const float4*)(Ar + idx);
            Lai[g] = *(const float4*)(Ai + idx);
            Lxr[g] = *(const float4*)(Xr + idx);
            Lxi[g] = *(const float4*)(Xi + idx);
        }
#pragma unroll
        for (int g = 0; g < G; ++g) {
            const float* pab = (const float*)&Lar[g];
            const float* pai = (const float*)&Lai[g];
            const float* pxr = (const float*)&Lxr[g];
            const float* pxi = (const float*)&Lxi[g];
#pragma unroll
            for (int k = 0; k < 4; ++k) {
                float nyr = pab[k] * yr[k] - pai[k] * yi[k] + pxr[k];
                float nyi = pab[k] * yi[k] + pai[k] * yr[k] + pxi[k];
                yr[k] = nyr; yi[k] = nyi;
            }
            size_t idx = base + (size_t)(t0 + g) * DIM;
            floatx4 o1 = (floatx4){yr[0], yi[0], yr[1], yi[1]};
            floatx4 o2 = (floatx4){yr[2], yi[2], yr[3], yi[3]};
            float* po = outf + 2 * idx;
            __builtin_nontemporal_store(o1, (floatx4*)(po));
            __builtin_nontemporal_store(o2, (floatx4*)(po + 4));
        }
    }
}

extern "C" void kernel_launch(void* const* d_in, const int* in_sizes, int n_in,
                              void* d_out, int out_size, void* d_ws, size_t ws_size,
                              hipStream_t stream)
{
    const float* Ar = (const float*)d_in[0];
    const float* Ai = (const float*)d_in[1];
    const float* Xr = (const float*)d_in[2];
    const float* Xi = (const float*)d_in[3];
    float* outf = (float*)d_out;
    float4* agg = (float4*)d_ws;

    dim3 block(256);

    if (ws_size >= (size_t)BATCH * 256 * DIM * sizeof(float4)) {
        constexpr int NT = 256, T = SEQ / 256;   // T = 16
        dim3 grid1((BATCH * NT) / 4);
        k_tile_agg<NT, T, 4><<<grid1, block, 0, stream>>>(Ar, Ai, Xr, Xi, agg);
        k_scan_agg<NT><<<(BATCH * DIM) / 4, block, 0, stream>>>(agg);
        k_apply<NT, T, 4><<<grid1, block, 0, stream>>>(Ar, Ai, Xr, Xi, agg, outf);
    } else {
        constexpr int NT = 64, T = SEQ / 64;     // T = 64
        dim3 grid1((BATCH * NT) / 4);
        k_tile_agg<NT, T, 4><<<grid1, block, 0, stream>>>(Ar, Ai, Xr, Xi, agg);
        k_scan_agg<NT><<<(BATCH * DIM) / 4, block, 0, stream>>>(agg);
        k_apply<NT, T, 4><<<grid1, block, 0, stream>>>(Ar, Ai, Xr, Xi, agg, outf);
    }
}